// Round 1
// baseline (919.976 us; speedup 1.0000x reference)
//
#include <hip/hip_runtime.h>

#pragma clang fp contract(off)

#define NPT 4096
#define B_ 16
#define S_ 1024
#define K_ 32
#define ROWS (B_*S_*K_)   // 524288
#define PNB 1024          // partial-stats blocks (layer kernels' grid)
#define NWORK 496         // worker blocks in head kernel (grid 512 = 16 fps + 496)
#define NCHUNK 512        // 16 batches * 32 chunks of 32 queries

typedef float v2f __attribute__((ext_vector_type(2)));
typedef unsigned int u32;
typedef unsigned long long u64;
typedef __attribute__((ext_vector_type(8))) short s16x8;
typedef __attribute__((ext_vector_type(4))) float f32x4;

__device__ __forceinline__ float rlf(float v, int l) {
  return __uint_as_float(__builtin_amdgcn_readlane(__float_as_uint(v), l));
}

__device__ __forceinline__ short rne_bf16(float x) {
  u32 b = __float_as_uint(x);
  b += 0x7FFFu + ((b >> 16) & 1u);
  return (short)(b >> 16);
}
__device__ __forceinline__ u32 rne_bits(float x) {   // rounded bits, result in high 16
  u32 b = __float_as_uint(x);
  return b + 0x7FFFu + ((b >> 16) & 1u);
}

__device__ __forceinline__ f32x4 mfma16(s16x8 a, s16x8 b, f32x4 c) {
  return __builtin_amdgcn_mfma_f32_16x16x32_bf16(a, b, c, 0, 0, 0);
}

// stored-position -> original channel permutation for y2 (layer2 fast stores)
__device__ __forceinline__ int permc(int p) { return ((p & 3) << 4) | (p >> 2); }

// BN+relu+RNE-pack for a bf16 pair held in one dword. Bit-exact vs scalar path.
__device__ __forceinline__ u32 bnrelu_pack(u32 d, v2f sc, v2f sh) {
  v2f a;
  a.x = __uint_as_float(d << 16);
  a.y = __uint_as_float(d & 0xFFFF0000u);
  v2f z = __builtin_elementwise_fma(a, sc, sh);
  z = __builtin_elementwise_max(z, (v2f){0.f, 0.f});
  u32 zx = rne_bits(z.x), zy = rne_bits(z.y);
  return __builtin_amdgcn_perm(zy, zx, 0x07060302);   // {zx.hi16, zy.hi16}
}

template <int CTRL>
__device__ __forceinline__ u64 dpp_u64(u64 x) {
  int lo = (int)(u32)x, hi = (int)(u32)(x >> 32);
  lo = __builtin_amdgcn_update_dpp(lo, lo, CTRL, 0xF, 0xF, false);
  hi = __builtin_amdgcn_update_dpp(hi, hi, CTRL, 0xF, 0xF, false);
  return ((u64)(u32)hi << 32) | (u32)lo;
}
// full-wave f64 max -> lane 63. Keys are positive doubles => f64 order == u64 order.
__device__ __forceinline__ double wave_max_f64(double k) {
  k = fmax(k, __longlong_as_double((long long)dpp_u64<0x111>((u64)__double_as_longlong(k))));
  k = fmax(k, __longlong_as_double((long long)dpp_u64<0x112>((u64)__double_as_longlong(k))));
  k = fmax(k, __longlong_as_double((long long)dpp_u64<0x114>((u64)__double_as_longlong(k))));
  k = fmax(k, __longlong_as_double((long long)dpp_u64<0x118>((u64)__double_as_longlong(k))));
  k = fmax(k, __longlong_as_double((long long)dpp_u64<0x142>((u64)__double_as_longlong(k))));
  k = fmax(k, __longlong_as_double((long long)dpp_u64<0x143>((u64)__double_as_longlong(k))));
  return k;
}

__device__ __forceinline__ double mkkey(float d, u32 lo) {
  return __longlong_as_double((long long)(((u64)__float_as_uint(d) << 32) | lo));
}

// ---------------- HEAD: fused FPS + ball-query + layer1 ----------------
// Blocks 0..15: FPS, one block per batch (FINAL R5/R8 structure, 588us = 1024 iter x ~1378
// cyc; wave-count curve + reduce restructures measured R5-R12 — DO NOT retune). Adds:
// incremental new_xyz store + per-32-iter release-publish of progress (wave-0 only, ~+1%).
// Blocks 16..511: workers. Each owns chunk cid (and cid+496 for cid<16): batch b=cid&15,
// queries c*32..c*32+31. Spin on prog[b] (agent acquire), then bit-exact ballq scan
// (4 queries/wave, shared coord loads, gidx kept in LDS) + bit-exact layer1 rows + stats.
// Co-residency: 512 blocks * 512thr, LDS ~73.8KB -> 2 blk/CU -> all resident (no deadlock);
// spins are fail-safe bounded regardless.
__global__ __launch_bounds__(512, 4) void head_kernel(
    const float* __restrict__ xyz, const float* __restrict__ pts,
    const float* __restrict__ W1, const float* __restrict__ b1,
    float* __restrict__ out0, float* __restrict__ new_xyz,
    int* __restrict__ prog, unsigned short* __restrict__ y1,
    float* __restrict__ partials) {
  __shared__ float4 spt[NPT];       // 64 KB (fps only)
  __shared__ u64 skey[3];           // fps only
  __shared__ int sfar[S_];          // fps: selection journal; worker: gidx scratch (1024 ints)
  __shared__ float spw[8 * 2 * 64]; // worker stats reduce
  const int bid = blockIdx.x;
  const int t = threadIdx.x;
  const int lane = t & 63;

  if (bid < B_) {
    // ================= FPS =================
    const int b = bid;
    const float* xb = xyz + (size_t)b * 3 * NPT;
#pragma unroll
    for (int j = 0; j < 8; j++) {
      int m = t + j * 512;
      spt[m] = make_float4(xb[m], xb[NPT + m], xb[2 * NPT + m], 0.f);
    }
    if (t < 3) skey[t] = 0ull;
    const float4* xb4 = (const float4*)xb;
    float4 X0 = xb4[t * 2], X1 = xb4[t * 2 + 1];
    float4 Y0 = xb4[NPT / 4 + t * 2], Y1 = xb4[NPT / 4 + t * 2 + 1];
    float4 Z0 = xb4[2 * NPT / 4 + t * 2], Z1 = xb4[2 * NPT / 4 + t * 2 + 1];
    v2f px[4], py[4], pz[4], ds[4];
    px[0] = (v2f){X0.x, X0.y}; px[1] = (v2f){X0.z, X0.w}; px[2] = (v2f){X1.x, X1.y}; px[3] = (v2f){X1.z, X1.w};
    py[0] = (v2f){Y0.x, Y0.y}; py[1] = (v2f){Y0.z, Y0.w}; py[2] = (v2f){Y1.x, Y1.y}; py[3] = (v2f){Y1.z, Y1.w};
    pz[0] = (v2f){Z0.x, Z0.y}; pz[1] = (v2f){Z0.z, Z0.w}; pz[2] = (v2f){Z1.x, Z1.y}; pz[3] = (v2f){Z1.z, Z1.w};
    const int base = t * 8;
    u32 lo[8];
#pragma unroll
    for (int i = 0; i < 8; i++) lo[i] = ~(u32)(base + i);
#pragma unroll
    for (int j = 0; j < 4; j++) ds[j] = (v2f){1e10f, 1e10f};
    __syncthreads();
    int far = 0, slot = 0;
    for (int it = 0; it < S_; ++it) {
      if (t == 0) sfar[it] = far;
      float4 c = spt[far];
      if (t == 0) {
        // incremental publish of centroid row `it` (fire-and-forget stores)
        float* nz = new_xyz + ((size_t)b * S_ + it) * 3;
        nz[0] = c.x; nz[1] = c.y; nz[2] = c.z;
        if ((it & 31) == 31) {
          // release: drains the stores above (wave-0 only, every 32 iters ~= +1%)
          __hip_atomic_store(&prog[b], it + 1, __ATOMIC_RELEASE, __HIP_MEMORY_SCOPE_AGENT);
        }
      }
      v2f cx = (v2f){c.x, c.x}, cy = (v2f){c.y, c.y}, cz = (v2f){c.z, c.z};
#pragma unroll
      for (int j = 0; j < 4; j++) {
        // exact ref op order per element: ((dx*dx + dy*dy) + dz*dz), contraction OFF
        v2f dx = px[j] - cx, dy = py[j] - cy, dz = pz[j] - cz;
        v2f s = dx * dx + dy * dy;
        v2f d = s + dz * dz;
        v2f nd;
        nd.x = fminf(ds[j].x, d.x);
        nd.y = fminf(ds[j].y, d.y);
        ds[j] = nd;
      }
      // f64 sortable keys: max dist, tie -> min index (via ~idx in low word)
      double k = fmax(fmax(fmax(mkkey(ds[0].x, lo[0]), mkkey(ds[0].y, lo[1])),
                           fmax(mkkey(ds[1].x, lo[2]), mkkey(ds[1].y, lo[3]))),
                      fmax(fmax(mkkey(ds[2].x, lo[4]), mkkey(ds[2].y, lo[5])),
                           fmax(mkkey(ds[3].x, lo[6]), mkkey(ds[3].y, lo[7]))));
      k = wave_max_f64(k);
      if (lane == 63) atomicMax(&skey[slot], (u64)__double_as_longlong(k));
      __syncthreads();
      u64 kk = skey[slot];
      if (t == 0) skey[slot == 0 ? 2 : slot - 1] = 0ull;  // reset slot (it+2)%3: safe post-barrier
      far = (int)(~(u32)kk);
      slot = (slot == 2) ? 0 : slot + 1;
    }
    __syncthreads();
    // coalesced writeback of out0 (new_xyz already written incrementally)
#pragma unroll
    for (int j = 0; j < 2; j++) {
      int it = t + j * 512;
      float4 p = spt[sfar[it]];
      out0[(b * 3 + 0) * S_ + it] = p.x;
      out0[(b * 3 + 1) * S_ + it] = p.y;
      out0[(b * 3 + 2) * S_ + it] = p.z;
    }
  } else {
    // ================= WORKER: ballq + layer1 =================
    const int wv = t >> 6;
    const int grp = lane >> 3;          // 0..7; groups 0..3 gather for rows A..D
    const int gc = lane & 7;            // channel slot within group (0..5 used)
    const int wkr = bid - B_;
    float w[6];
#pragma unroll
    for (int cc = 0; cc < 6; cc++) w[cc] = W1[lane * 6 + cc];
    const float bias = b1[lane];
    float s0 = 0.f, s1 = 0.f;
    int* glds = sfar;                   // 1024 ints: [wave][4 queries][32 idx]

    for (int cid = wkr; cid < NCHUNK; cid += NWORK) {
      const int b = cid & 15, cch = cid >> 4;
      if (t == 0) {
        const int tgt = (cch + 1) * 32;
        int spins = 0;
        while (__hip_atomic_load(&prog[b], __ATOMIC_ACQUIRE, __HIP_MEMORY_SCOPE_AGENT) < tgt) {
          __builtin_amdgcn_s_sleep(8);
          if (++spins > (1 << 20)) break;   // fail-safe: never hang the device
        }
      }
      __syncthreads();

      // ---- ball query: 4 queries per wave, shared coordinate loads (bit-exact vs ballq) ----
      const float* xb = xyz + (size_t)b * 3 * NPT;
      const int q0 = cch * 32 + wv * 4;         // local query base in batch
      const int sg0 = b * 1024 + q0;            // global query base
      float qx[4], qy[4], qz[4];
      int cnt[4], fi[4];
#pragma unroll
      for (int j = 0; j < 4; j++) {
        qx[j] = new_xyz[(size_t)(sg0 + j) * 3 + 0];
        qy[j] = new_xyz[(size_t)(sg0 + j) * 3 + 1];
        qz[j] = new_xyz[(size_t)(sg0 + j) * 3 + 2];
        cnt[j] = 0; fi[j] = 0x7fffffff;
      }
      const float R2 = (float)(0.4 * 0.4);
      int* gl = glds + wv * 4 * K_;
      for (int c0 = 0; c0 < NPT; c0 += 64) {
        if (cnt[0] >= K_ && cnt[1] >= K_ && cnt[2] >= K_ && cnt[3] >= K_) break;
        int n = c0 + lane;
        float x = xb[n], y = xb[NPT + n], z = xb[2 * NPT + n];
#pragma unroll
        for (int j = 0; j < 4; j++) {
          if (cnt[j] < K_) {                    // wave-uniform guard: identical writes vs ballq
            float dx = __fadd_rn(qx[j], -x);
            float dy = __fadd_rn(qy[j], -y);
            float dz = __fadd_rn(qz[j], -z);
            float sq = __fadd_rn(__fadd_rn(__fmul_rn(dx, dx), __fmul_rn(dy, dy)), __fmul_rn(dz, dz));
            bool inr = !(sq > R2);
            unsigned long long m = __ballot(inr);
            if (inr) {
              int pos = cnt[j] + (int)__popcll(m & ((1ull << lane) - 1ull));
              if (pos < K_) gl[j * K_ + pos] = n;
            }
            if (fi[j] == 0x7fffffff && m) fi[j] = c0 + (int)__builtin_ctzll(m);
            cnt[j] += (int)__popcll(m);
          }
        }
      }
#pragma unroll
      for (int j = 0; j < 4; j++)
        if (lane >= cnt[j] && lane < K_) gl[j * K_ + lane] = fi[j];
      __syncthreads();

      // ---- layer1: 4 queries x 32 rows, 4 rows per iter (bit-exact vs layer1_kernel) ----
      for (int it = 0; it < 32; ++it) {
        const int j = it >> 3, k4 = (it & 7) * 4;
        const int sg = sg0 + j;                 // global query (== rr>>5)
        float v = 0.f;
        if (grp < 4 && gc < 6) {
          int gi = gl[j * K_ + k4 + grp];
          if (gc < 3) v = xyz[((size_t)b * 3 + gc) * NPT + gi] - new_xyz[(size_t)sg * 3 + gc];
          else        v = pts[((size_t)b * 3 + (gc - 3)) * NPT + gi];
        }
        float acc[4];
#pragma unroll
        for (int q = 0; q < 4; q++) acc[q] = bias;
#pragma unroll
        for (int cc = 0; cc < 6; cc++) {
#pragma unroll
          for (int q = 0; q < 4; q++) acc[q] = fmaf(rlf(v, q * 8 + cc), w[cc], acc[q]);
        }
        const size_t rbase = (size_t)sg * K_ + k4;
#pragma unroll
        for (int q = 0; q < 4; q++) {
          y1[(rbase + q) * 64 + lane] = (unsigned short)rne_bf16(acc[q]);
          s0 += acc[q]; s1 = fmaf(acc[q], acc[q], s1);
        }
      }
      __syncthreads();    // protect glds before next chunk reuse
    }

    // ---- stats partials: reduce 8 waves, write slot wkr (finalize1 reads NWORK slots) ----
    spw[(wv * 2 + 0) * 64 + lane] = s0;
    spw[(wv * 2 + 1) * 64 + lane] = s1;
    __syncthreads();
    if (t < 128) {
      float p = 0.f;
#pragma unroll
      for (int ww = 0; ww < 8; ww++) p += spw[ww * 128 + t];
      partials[(size_t)t * PNB + wkr] = p;
    }
  }
}

// ---------------- fold partials -> bn scale/shift (pnb = #valid slots) ----------------
__global__ __launch_bounds__(256) void finalize_kernel(const float* __restrict__ partials,
    int cout, int pnb, const float* __restrict__ g, const float* __restrict__ be,
    float* __restrict__ bn) {
  const int c = blockIdx.x;
  const int t = threadIdx.x;
  const int lane = t & 63, wv = t >> 6;
  float s0 = 0.f, s1 = 0.f;
  for (int bb = t; bb < pnb; bb += 256) {
    s0 += partials[(size_t)c * PNB + bb];
    s1 += partials[(size_t)(cout + c) * PNB + bb];
  }
#pragma unroll
  for (int off = 32; off; off >>= 1) {
    s0 += __shfl_xor(s0, off);
    s1 += __shfl_xor(s1, off);
  }
  __shared__ float r0[4], r1[4];
  if (lane == 0) { r0[wv] = s0; r1[wv] = s1; }
  __syncthreads();
  if (t == 0) {
    double d0 = (double)r0[0] + r0[1] + r0[2] + r0[3];
    double d1 = (double)r1[0] + r1[1] + r1[2] + r1[3];
    double N = (double)ROWS;
    double mean = d0 / N;
    double var = d1 / N - mean * mean;
    double scale = (double)g[c] / sqrt(var + 1e-5);
    bn[c] = (float)scale;
    bn[cout + c] = (float)((double)be[c] - mean * scale);
  }
}

// ---------------- Layer 2 (MFMA): bn1+relu (pk) -> GEMM 64->64, 2 M-tiles/iter; permuted-K ----
__global__ __launch_bounds__(256) void layer2_kernel(
    const unsigned short* __restrict__ y1, const float* __restrict__ W,
    const float* __restrict__ bias, const float* __restrict__ bnin,
    unsigned short* __restrict__ y2, float* __restrict__ partials) {
  constexpr int NT = 4;
  const int lane = threadIdx.x & 63, wv = threadIdx.x >> 6;
  const int quad = lane >> 4, l16 = lane & 15;
  s16x8 bfrag[NT][2];
  float biasr[NT];
#pragma unroll
  for (int t = 0; t < NT; t++) {
    int n = l16 + 16 * t;
    biasr[t] = bias[n];
#pragma unroll
    for (int kc = 0; kc < 2; kc++)
#pragma unroll
      for (int j = 0; j < 8; j++)
        bfrag[t][kc][j] = rne_bf16(W[(size_t)n * 64 + kc * 32 + quad * 8 + j]);
  }
  v2f sc2[2][4], sh2[2][4];
#pragma unroll
  for (int kc = 0; kc < 2; kc++)
#pragma unroll
    for (int p = 0; p < 4; p++) {
      int k0 = kc * 32 + quad * 8 + 2 * p;
      sc2[kc][p] = (v2f){bnin[k0], bnin[k0 + 1]};
      sh2[kc][p] = (v2f){bnin[64 + k0], bnin[64 + k0 + 1]};
    }
  float s0[NT], s1[NT];
#pragma unroll
  for (int t = 0; t < NT; t++) { s0[t] = 0.f; s1[t] = 0.f; }
  const int nwaves = gridDim.x * 4;
  for (int mt = (blockIdx.x * 4 + wv) * 2; mt < ROWS / 16; mt += nwaves * 2) {
    const u32* p0 = (const u32*)(y1 + (size_t)(mt * 16 + l16) * 64 + quad * 8);
    const u32* p1 = (const u32*)(y1 + (size_t)((mt + 1) * 16 + l16) * 64 + quad * 8);
    u32 d[2][8];
#pragma unroll
    for (int q = 0; q < 4; q++) { d[0][q] = p0[q]; d[0][4 + q] = p0[16 + q]; }
#pragma unroll
    for (int q = 0; q < 4; q++) { d[1][q] = p1[q]; d[1][4 + q] = p1[16 + q]; }
    s16x8 a[2][2];
#pragma unroll
    for (int m2 = 0; m2 < 2; m2++) {
      u32* a0u = (u32*)&a[m2][0]; u32* a1u = (u32*)&a[m2][1];
#pragma unroll
      for (int q = 0; q < 4; q++) {
        a0u[q] = bnrelu_pack(d[m2][q], sc2[0][q], sh2[0][q]);
        a1u[q] = bnrelu_pack(d[m2][4 + q], sc2[1][q], sh2[1][q]);
      }
    }
    f32x4 acc[2][NT];
#pragma unroll
    for (int m2 = 0; m2 < 2; m2++)
#pragma unroll
      for (int t = 0; t < NT; t++) {
        acc[m2][t] = (f32x4){biasr[t], biasr[t], biasr[t], biasr[t]};
        acc[m2][t] = mfma16(a[m2][0], bfrag[t][0], acc[m2][t]);
        acc[m2][t] = mfma16(a[m2][1], bfrag[t][1], acc[m2][t]);
      }
#pragma unroll
    for (int m2 = 0; m2 < 2; m2++) {
#pragma unroll
      for (int r = 0; r < 4; r++) {
        u32 b01 = __builtin_amdgcn_perm(rne_bits(acc[m2][1][r]), rne_bits(acc[m2][0][r]), 0x07060302);
        u32 b23 = __builtin_amdgcn_perm(rne_bits(acc[m2][3][r]), rne_bits(acc[m2][2][r]), 0x07060302);
        int m = (mt + m2) * 16 + quad * 4 + r;
        *(uint2*)(y2 + (size_t)m * 64 + 4 * l16) = make_uint2(b01, b23);
      }
#pragma unroll
      for (int t = 0; t < NT; t++)
#pragma unroll
        for (int r = 0; r < 4; r++) {
          float v = acc[m2][t][r];
          s0[t] += v; s1[t] = fmaf(v, v, s1[t]);
        }
    }
  }
#pragma unroll
  for (int t = 0; t < NT; t++) {
    s0[t] += __shfl_xor(s0[t], 16); s0[t] += __shfl_xor(s0[t], 32);
    s1[t] += __shfl_xor(s1[t], 16); s1[t] += __shfl_xor(s1[t], 32);
  }
  __shared__ float sp[4 * 2 * 64];
  if (quad == 0) {
#pragma unroll
    for (int t = 0; t < NT; t++) {
      sp[wv * 128 + l16 + 16 * t] = s0[t];
      sp[wv * 128 + 64 + l16 + 16 * t] = s1[t];
    }
  }
  __syncthreads();
  if (threadIdx.x < 128) {
    int tt = threadIdx.x;
    float p = sp[tt] + sp[128 + tt] + sp[256 + tt] + sp[384 + tt];
    partials[(size_t)tt * PNB + blockIdx.x] = p;
  }
}

// ---------------- Fused layer3: GEMM once (permuted-K input) -> stats + per-group min/max ----
__global__ __launch_bounds__(256) void l3fused_kernel(
    const unsigned short* __restrict__ y2, const float* __restrict__ W3,
    const float* __restrict__ b3, const float* __restrict__ bn2,
    float* __restrict__ mnbuf, float* __restrict__ mxbuf,   // [b][ch][s] f32
    float* __restrict__ partials) {
  constexpr int NT = 8;
  const int lane = threadIdx.x & 63, wv = threadIdx.x >> 6;
  const int quad = lane >> 4, l16 = lane & 15;
  s16x8 bfrag[NT][2];
  float biasr[NT];
#pragma unroll
  for (int t = 0; t < NT; t++) {
    int n = l16 + 16 * t;
    biasr[t] = b3[n];
#pragma unroll
    for (int kc = 0; kc < 2; kc++)
#pragma unroll
      for (int j = 0; j < 8; j++)
        bfrag[t][kc][j] = rne_bf16(W3[(size_t)n * 64 + permc(kc * 32 + quad * 8 + j)]);
  }
  v2f sc2[2][4], sh2[2][4];
#pragma unroll
  for (int kc = 0; kc < 2; kc++)
#pragma unroll
    for (int p = 0; p < 4; p++) {
      int c0 = permc(kc * 32 + quad * 8 + 2 * p);
      int c1 = permc(kc * 32 + quad * 8 + 2 * p + 1);
      sc2[kc][p] = (v2f){bn2[c0], bn2[c1]};
      sh2[kc][p] = (v2f){bn2[64 + c0], bn2[64 + c1]};
    }
  float s0[NT], s1[NT];
#pragma unroll
  for (int t = 0; t < NT; t++) { s0[t] = 0.f; s1[t] = 0.f; }
  __shared__ float tmx[128 * 4], tmn[128 * 4];
  for (int g0 = blockIdx.x; g0 < 4096; g0 += 1024) {
    const int gq = g0 * 4 + wv;
    float mx[NT], mn[NT];
#pragma unroll
    for (int t = 0; t < NT; t++) { mx[t] = -1e30f; mn[t] = 1e30f; }
#pragma unroll
    for (int mt2 = 0; mt2 < 2; mt2++) {
      int row = gq * 32 + mt2 * 16 + l16;
      const u32* p = (const u32*)(y2 + (size_t)row * 64 + quad * 8);
      s16x8 a0, a1;
      u32* a0u = (u32*)&a0; u32* a1u = (u32*)&a1;
#pragma unroll
      for (int q = 0; q < 4; q++) {
        a0u[q] = bnrelu_pack(p[q], sc2[0][q], sh2[0][q]);
        a1u[q] = bnrelu_pack(p[16 + q], sc2[1][q], sh2[1][q]);
      }
#pragma unroll
      for (int t = 0; t < NT; t++) {
        f32x4 acc = (f32x4){biasr[t], biasr[t], biasr[t], biasr[t]};
        acc = mfma16(a0, bfrag[t][0], acc);
        acc = mfma16(a1, bfrag[t][1], acc);
#pragma unroll
        for (int r = 0; r < 4; r++) {
          float v = acc[r];
          s0[t] += v; s1[t] = fmaf(v, v, s1[t]);
          mx[t] = fmaxf(mx[t], v); mn[t] = fminf(mn[t], v);
        }
      }
    }
#pragma unroll
    for (int t = 0; t < NT; t++) {
      mx[t] = fmaxf(mx[t], __shfl_xor(mx[t], 16));
      mx[t] = fmaxf(mx[t], __shfl_xor(mx[t], 32));
      mn[t] = fminf(mn[t], __shfl_xor(mn[t], 16));
      mn[t] = fminf(mn[t], __shfl_xor(mn[t], 32));
    }
    if (quad == 0) {
#pragma unroll
      for (int t = 0; t < NT; t++) {
        tmx[(l16 + 16 * t) * 4 + wv] = mx[t];
        tmn[(l16 + 16 * t) * 4 + wv] = mn[t];
      }
    }
    __syncthreads();
    if (threadIdx.x < 128) {
      int b = g0 >> 8;
      int s0i = (g0 & 255) * 4;
      size_t o = ((size_t)b * 128 + threadIdx.x) * 1024 + s0i;
      *(float4*)&mxbuf[o] = *(float4*)&tmx[threadIdx.x * 4];
      *(float4*)&mnbuf[o] = *(float4*)&tmn[threadIdx.x * 4];
    }
    __syncthreads();
  }
#pragma unroll
  for (int t = 0; t < NT; t++) {
    s0[t] += __shfl_xor(s0[t], 16); s0[t] += __shfl_xor(s0[t], 32);
    s1[t] += __shfl_xor(s1[t], 16); s1[t] += __shfl_xor(s1[t], 32);
  }
  __shared__ float sp[4 * 2 * 128];
  if (quad == 0) {
#pragma unroll
    for (int t = 0; t < NT; t++) {
      sp[wv * 256 + l16 + 16 * t] = s0[t];
      sp[wv * 256 + 128 + l16 + 16 * t] = s1[t];
    }
  }
  __syncthreads();
  {
    int tt = threadIdx.x;
    float p = sp[tt] + sp[256 + tt] + sp[512 + tt] + sp[768 + tt];
    partials[(size_t)tt * PNB + blockIdx.x] = p;
  }
}

// ---------------- fused finalize3 + apply: each block covers exactly ONE channel ------------
__global__ __launch_bounds__(256) void l3final_kernel(
    const float* __restrict__ partials, const float* __restrict__ g,
    const float* __restrict__ be, const float* __restrict__ mnbuf,
    const float* __restrict__ mxbuf, float* __restrict__ out1) {
  const int t = threadIdx.x;
  const int ch = (blockIdx.x >> 2) & 127;
  const int lane = t & 63, wv = t >> 6;
  float s0 = 0.f, s1 = 0.f;
  for (int bb = t; bb < PNB; bb += 256) {
    s0 += partials[(size_t)ch * PNB + bb];
    s1 += partials[(size_t)(128 + ch) * PNB + bb];
  }
#pragma unroll
  for (int off = 32; off; off >>= 1) {
    s0 += __shfl_xor(s0, off);
    s1 += __shfl_xor(s1, off);
  }
  __shared__ float r0[4], r1[4];
  __shared__ float bnsh[2];
  if (lane == 0) { r0[wv] = s0; r1[wv] = s1; }
  __syncthreads();
  if (t == 0) {
    double d0 = (double)r0[0] + r0[1] + r0[2] + r0[3];
    double d1 = (double)r1[0] + r1[1] + r1[2] + r1[3];
    double N = (double)ROWS;
    double mean = d0 / N;
    double var = d1 / N - mean * mean;
    double scale = (double)g[ch] / sqrt(var + 1e-5);
    bnsh[0] = (float)scale;
    bnsh[1] = (float)((double)be[ch] - mean * scale);
  }
  __syncthreads();
  float s = bnsh[0], h = bnsh[1];
  int i = blockIdx.x * 256 + t;
  float v = (s > 0.f) ? mxbuf[i] : mnbuf[i];
  out1[i] = fmaxf(fmaf(v, s, h), 0.f);
}

extern "C" void kernel_launch(void* const* d_in, const int* in_sizes, int n_in,
                              void* d_out, int out_size, void* d_ws, size_t ws_size,
                              hipStream_t stream) {
  const float* xyz = (const float*)d_in[0];
  const float* pts = (const float*)d_in[1];
  const float* W1 = (const float*)d_in[2],  *b1 = (const float*)d_in[3];
  const float* g1 = (const float*)d_in[4],  *be1 = (const float*)d_in[5];
  const float* W2 = (const float*)d_in[6],  *b2 = (const float*)d_in[7];
  const float* g2 = (const float*)d_in[8],  *be2 = (const float*)d_in[9];
  const float* W3 = (const float*)d_in[10], *b3 = (const float*)d_in[11];
  const float* g3 = (const float*)d_in[12], *be3 = (const float*)d_in[13];
  float* out0 = (float*)d_out;                 // xyz_query_pc [16,3,1024]
  float* out1 = out0 + B_ * 3 * S_;            // new_points   [16,128,1024]

  char* ws = (char*)d_ws;
  float* new_xyz  = (float*)(ws);
  float* bn1      = (float*)(ws + 196608);
  float* bn2      = bn1 + 128;
  int*   prog     = (int*)(ws + 198656);                           // 16 ints (old gidx spot)
  float* partials = (float*)(ws + 2295808);
  unsigned short* y1 = (unsigned short*)(ws + 4392960);            // 64 MB bf16
  unsigned short* y2 = (unsigned short*)(ws + 4392960 + 67108864); // 64 MB bf16 (K-permuted)
  float* mnbuf = (float*)(ws + 4392960);                           // reuse y1 space
  float* mxbuf = (float*)(ws + 4392960 + 8388608);

  hipMemsetAsync(prog, 0, 64, stream);   // reset progress flags each replay
  head_kernel<<<B_ + NWORK, 512, 0, stream>>>(xyz, pts, W1, b1, out0, new_xyz, prog, y1, partials);
  finalize_kernel<<<64, 256, 0, stream>>>(partials, 64, NWORK, g1, be1, bn1);
  layer2_kernel<<<PNB, 256, 0, stream>>>(y1, W2, b2, bn1, y2, partials);
  finalize_kernel<<<64, 256, 0, stream>>>(partials, 64, PNB, g2, be2, bn2);
  l3fused_kernel<<<PNB, 256, 0, stream>>>(y2, W3, b3, bn2, mnbuf, mxbuf, partials);
  l3final_kernel<<<8192, 256, 0, stream>>>(partials, g3, be3, mnbuf, mxbuf, out1);
}

// Round 2
// 890.429 us; speedup vs baseline: 1.0332x; 1.0332x over previous
//
#include <hip/hip_runtime.h>

#pragma clang fp contract(off)

#define NPT 4096
#define B_ 16
#define S_ 1024
#define K_ 32
#define ROWS (B_*S_*K_)   // 524288
#define PNB 1024          // partial-stats blocks (layer kernels' grid)
#define NWORK 240         // worker blocks in head kernel (grid 256 = 16 fps + 240, 1 blk/CU)
#define NCHUNK 512        // 16 batches * 32 chunks of 32 queries

typedef float v2f __attribute__((ext_vector_type(2)));
typedef unsigned int u32;
typedef unsigned long long u64;
typedef __attribute__((ext_vector_type(8))) short s16x8;
typedef __attribute__((ext_vector_type(4))) float f32x4;

__device__ __forceinline__ float rlf(float v, int l) {
  return __uint_as_float(__builtin_amdgcn_readlane(__float_as_uint(v), l));
}

__device__ __forceinline__ short rne_bf16(float x) {
  u32 b = __float_as_uint(x);
  b += 0x7FFFu + ((b >> 16) & 1u);
  return (short)(b >> 16);
}
__device__ __forceinline__ u32 rne_bits(float x) {   // rounded bits, result in high 16
  u32 b = __float_as_uint(x);
  return b + 0x7FFFu + ((b >> 16) & 1u);
}

__device__ __forceinline__ f32x4 mfma16(s16x8 a, s16x8 b, f32x4 c) {
  return __builtin_amdgcn_mfma_f32_16x16x32_bf16(a, b, c, 0, 0, 0);
}

// stored-position -> original channel permutation for y2 (layer2 fast stores)
__device__ __forceinline__ int permc(int p) { return ((p & 3) << 4) | (p >> 2); }

// BN+relu+RNE-pack for a bf16 pair held in one dword. Bit-exact vs scalar path.
__device__ __forceinline__ u32 bnrelu_pack(u32 d, v2f sc, v2f sh) {
  v2f a;
  a.x = __uint_as_float(d << 16);
  a.y = __uint_as_float(d & 0xFFFF0000u);
  v2f z = __builtin_elementwise_fma(a, sc, sh);
  z = __builtin_elementwise_max(z, (v2f){0.f, 0.f});
  u32 zx = rne_bits(z.x), zy = rne_bits(z.y);
  return __builtin_amdgcn_perm(zy, zx, 0x07060302);   // {zx.hi16, zy.hi16}
}

template <int CTRL>
__device__ __forceinline__ u64 dpp_u64(u64 x) {
  int lo = (int)(u32)x, hi = (int)(u32)(x >> 32);
  lo = __builtin_amdgcn_update_dpp(lo, lo, CTRL, 0xF, 0xF, false);
  hi = __builtin_amdgcn_update_dpp(hi, hi, CTRL, 0xF, 0xF, false);
  return ((u64)(u32)hi << 32) | (u32)lo;
}
// full-wave f64 max -> lane 63. Keys are positive doubles => f64 order == u64 order.
__device__ __forceinline__ double wave_max_f64(double k) {
  k = fmax(k, __longlong_as_double((long long)dpp_u64<0x111>((u64)__double_as_longlong(k))));
  k = fmax(k, __longlong_as_double((long long)dpp_u64<0x112>((u64)__double_as_longlong(k))));
  k = fmax(k, __longlong_as_double((long long)dpp_u64<0x114>((u64)__double_as_longlong(k))));
  k = fmax(k, __longlong_as_double((long long)dpp_u64<0x118>((u64)__double_as_longlong(k))));
  k = fmax(k, __longlong_as_double((long long)dpp_u64<0x142>((u64)__double_as_longlong(k))));
  k = fmax(k, __longlong_as_double((long long)dpp_u64<0x143>((u64)__double_as_longlong(k))));
  return k;
}

__device__ __forceinline__ double mkkey(float d, u32 lo) {
  return __longlong_as_double((long long)(((u64)__float_as_uint(d) << 32) | lo));
}

// ---------------- HEAD: fused FPS + ball-query + layer1 ----------------
// Blocks 0..15: FPS, one block per batch (FINAL R5/R8 structure; wave-count curve + reduce
// restructures measured R5-R12 — DO NOT retune the core loop). Publish policy (R1 lesson):
// NO per-iteration global stores — wave-0's vmcnt(0) drain at every __syncthreads cost
// ~330 cyc/iter (589->731us). Instead: journal in sfar (already needed) and publish 32
// centroids in bulk at (it&31)==0 via lanes 0..31 of wave 0, one agent-release per 32 iters
// (per-wave vmcnt covers all 32 lanes' stores). Amortized ~4us total.
// LDS padded >81920B to force 1 block/CU (R1 lesson #2): FPS blocks must NOT share SIMDs
// with worker waves — the serial loop is issue-latency-critical. 256 blocks / 256 CUs.
// Blocks 16..255: workers. Chunk cid: batch b=cid&15, queries (cid>>4)*32..+31. Spin on
// prog[b] (agent acquire, s_sleep, bounded fail-safe), then bit-exact ballq scan
// (4 queries/wave, shared coord loads, gidx in LDS) + bit-exact layer1 rows + stats.
// Correctness never depends on co-residency: FPS never waits on workers; worker spins are
// bounded; if workers serialize after FPS they still read prog=final and compute correctly.
__global__ __launch_bounds__(512, 4) void head_kernel(
    const float* __restrict__ xyz, const float* __restrict__ pts,
    const float* __restrict__ W1, const float* __restrict__ b1,
    float* __restrict__ out0, float* __restrict__ new_xyz,
    int* __restrict__ prog, unsigned short* __restrict__ y1,
    float* __restrict__ partials) {
  __shared__ float4 spt[NPT + 520]; // 64KB + 8320B pad -> LDS 82560B > 81920 => 1 block/CU
  __shared__ u64 skey[3];           // fps only
  __shared__ int sfar[S_];          // fps: selection journal; worker: gidx scratch (1024 ints)
  __shared__ float spw[8 * 2 * 64]; // worker stats reduce
  const int bid = blockIdx.x;
  const int t = threadIdx.x;
  const int lane = t & 63;

  if (bid < B_) {
    // ================= FPS =================
    const int b = bid;
    const float* xb = xyz + (size_t)b * 3 * NPT;
#pragma unroll
    for (int j = 0; j < 8; j++) {
      int m = t + j * 512;
      spt[m] = make_float4(xb[m], xb[NPT + m], xb[2 * NPT + m], 0.f);
    }
    if (t < 3) skey[t] = 0ull;
    const float4* xb4 = (const float4*)xb;
    float4 X0 = xb4[t * 2], X1 = xb4[t * 2 + 1];
    float4 Y0 = xb4[NPT / 4 + t * 2], Y1 = xb4[NPT / 4 + t * 2 + 1];
    float4 Z0 = xb4[2 * NPT / 4 + t * 2], Z1 = xb4[2 * NPT / 4 + t * 2 + 1];
    v2f px[4], py[4], pz[4], ds[4];
    px[0] = (v2f){X0.x, X0.y}; px[1] = (v2f){X0.z, X0.w}; px[2] = (v2f){X1.x, X1.y}; px[3] = (v2f){X1.z, X1.w};
    py[0] = (v2f){Y0.x, Y0.y}; py[1] = (v2f){Y0.z, Y0.w}; py[2] = (v2f){Y1.x, Y1.y}; py[3] = (v2f){Y1.z, Y1.w};
    pz[0] = (v2f){Z0.x, Z0.y}; pz[1] = (v2f){Z0.z, Z0.w}; pz[2] = (v2f){Z1.x, Z1.y}; pz[3] = (v2f){Z1.z, Z1.w};
    const int base = t * 8;
    u32 lo[8];
#pragma unroll
    for (int i = 0; i < 8; i++) lo[i] = ~(u32)(base + i);
#pragma unroll
    for (int j = 0; j < 4; j++) ds[j] = (v2f){1e10f, 1e10f};
    __syncthreads();
    int far = 0, slot = 0;
    for (int it = 0; it < S_; ++it) {
      if (t == 0) sfar[it] = far;
      // bulk publish of centroid rows [it-32, it): wave-0 lanes 0..31 store, lane 0 releases.
      // sfar[it-1] was written at top of it-1 and a barrier intervened -> visible here.
      if ((it & 31) == 0 && it != 0) {
        if (t < 32) {
          int pit = it - 32 + t;
          float4 p = spt[sfar[pit]];
          float* nz = new_xyz + ((size_t)b * S_ + pit) * 3;
          nz[0] = p.x; nz[1] = p.y; nz[2] = p.z;
        }
        if (t == 0)
          __hip_atomic_store(&prog[b], it, __ATOMIC_RELEASE, __HIP_MEMORY_SCOPE_AGENT);
      }
      float4 c = spt[far];
      v2f cx = (v2f){c.x, c.x}, cy = (v2f){c.y, c.y}, cz = (v2f){c.z, c.z};
#pragma unroll
      for (int j = 0; j < 4; j++) {
        // exact ref op order per element: ((dx*dx + dy*dy) + dz*dz), contraction OFF
        v2f dx = px[j] - cx, dy = py[j] - cy, dz = pz[j] - cz;
        v2f s = dx * dx + dy * dy;
        v2f d = s + dz * dz;
        v2f nd;
        nd.x = fminf(ds[j].x, d.x);
        nd.y = fminf(ds[j].y, d.y);
        ds[j] = nd;
      }
      // f64 sortable keys: max dist, tie -> min index (via ~idx in low word)
      double k = fmax(fmax(fmax(mkkey(ds[0].x, lo[0]), mkkey(ds[0].y, lo[1])),
                           fmax(mkkey(ds[1].x, lo[2]), mkkey(ds[1].y, lo[3]))),
                      fmax(fmax(mkkey(ds[2].x, lo[4]), mkkey(ds[2].y, lo[5])),
                           fmax(mkkey(ds[3].x, lo[6]), mkkey(ds[3].y, lo[7]))));
      k = wave_max_f64(k);
      if (lane == 63) atomicMax(&skey[slot], (u64)__double_as_longlong(k));
      __syncthreads();
      u64 kk = skey[slot];
      if (t == 0) skey[slot == 0 ? 2 : slot - 1] = 0ull;  // reset slot (it+2)%3: safe post-barrier
      far = (int)(~(u32)kk);
      slot = (slot == 2) ? 0 : slot + 1;
    }
    __syncthreads();
    // final publish: rows 992..1023, then prog=1024 (before out0 writeback so release's
    // vmcnt drain doesn't also wait on the writeback stores)
    if (t < 32) {
      int pit = 992 + t;
      float4 p = spt[sfar[pit]];
      float* nz = new_xyz + ((size_t)b * S_ + pit) * 3;
      nz[0] = p.x; nz[1] = p.y; nz[2] = p.z;
    }
    if (t == 0)
      __hip_atomic_store(&prog[b], S_, __ATOMIC_RELEASE, __HIP_MEMORY_SCOPE_AGENT);
    // coalesced writeback of out0
#pragma unroll
    for (int j = 0; j < 2; j++) {
      int it = t + j * 512;
      float4 p = spt[sfar[it]];
      out0[(b * 3 + 0) * S_ + it] = p.x;
      out0[(b * 3 + 1) * S_ + it] = p.y;
      out0[(b * 3 + 2) * S_ + it] = p.z;
    }
  } else {
    // ================= WORKER: ballq + layer1 =================
    const int wv = t >> 6;
    const int grp = lane >> 3;          // 0..7; groups 0..3 gather for rows A..D
    const int gc = lane & 7;            // channel slot within group (0..5 used)
    const int wkr = bid - B_;
    float w[6];
#pragma unroll
    for (int cc = 0; cc < 6; cc++) w[cc] = W1[lane * 6 + cc];
    const float bias = b1[lane];
    float s0 = 0.f, s1 = 0.f;
    int* glds = sfar;                   // 1024 ints: [wave][4 queries][32 idx]

    for (int cid = wkr; cid < NCHUNK; cid += NWORK) {
      const int b = cid & 15, cch = cid >> 4;
      if (t == 0) {
        const int tgt = (cch + 1) * 32;
        int spins = 0;
        while (__hip_atomic_load(&prog[b], __ATOMIC_ACQUIRE, __HIP_MEMORY_SCOPE_AGENT) < tgt) {
          __builtin_amdgcn_s_sleep(8);
          if (++spins > (1 << 20)) break;   // fail-safe: never hang the device
        }
      }
      __syncthreads();

      // ---- ball query: 4 queries per wave, shared coordinate loads (bit-exact vs ballq) ----
      const float* xb = xyz + (size_t)b * 3 * NPT;
      const int q0 = cch * 32 + wv * 4;         // local query base in batch
      const int sg0 = b * 1024 + q0;            // global query base
      float qx[4], qy[4], qz[4];
      int cnt[4], fi[4];
#pragma unroll
      for (int j = 0; j < 4; j++) {
        qx[j] = new_xyz[(size_t)(sg0 + j) * 3 + 0];
        qy[j] = new_xyz[(size_t)(sg0 + j) * 3 + 1];
        qz[j] = new_xyz[(size_t)(sg0 + j) * 3 + 2];
        cnt[j] = 0; fi[j] = 0x7fffffff;
      }
      const float R2 = (float)(0.4 * 0.4);
      int* gl = glds + wv * 4 * K_;
      for (int c0 = 0; c0 < NPT; c0 += 64) {
        if (cnt[0] >= K_ && cnt[1] >= K_ && cnt[2] >= K_ && cnt[3] >= K_) break;
        int n = c0 + lane;
        float x = xb[n], y = xb[NPT + n], z = xb[2 * NPT + n];
#pragma unroll
        for (int j = 0; j < 4; j++) {
          if (cnt[j] < K_) {                    // wave-uniform guard: identical writes vs ballq
            float dx = __fadd_rn(qx[j], -x);
            float dy = __fadd_rn(qy[j], -y);
            float dz = __fadd_rn(qz[j], -z);
            float sq = __fadd_rn(__fadd_rn(__fmul_rn(dx, dx), __fmul_rn(dy, dy)), __fmul_rn(dz, dz));
            bool inr = !(sq > R2);
            unsigned long long m = __ballot(inr);
            if (inr) {
              int pos = cnt[j] + (int)__popcll(m & ((1ull << lane) - 1ull));
              if (pos < K_) gl[j * K_ + pos] = n;
            }
            if (fi[j] == 0x7fffffff && m) fi[j] = c0 + (int)__builtin_ctzll(m);
            cnt[j] += (int)__popcll(m);
          }
        }
      }
#pragma unroll
      for (int j = 0; j < 4; j++)
        if (lane >= cnt[j] && lane < K_) gl[j * K_ + lane] = fi[j];
      __syncthreads();

      // ---- layer1: 4 queries x 32 rows, 4 rows per iter (bit-exact vs layer1_kernel) ----
      for (int it = 0; it < 32; ++it) {
        const int j = it >> 3, k4 = (it & 7) * 4;
        const int sg = sg0 + j;                 // global query (== rr>>5)
        float v = 0.f;
        if (grp < 4 && gc < 6) {
          int gi = gl[j * K_ + k4 + grp];
          if (gc < 3) v = xyz[((size_t)b * 3 + gc) * NPT + gi] - new_xyz[(size_t)sg * 3 + gc];
          else        v = pts[((size_t)b * 3 + (gc - 3)) * NPT + gi];
        }
        float acc[4];
#pragma unroll
        for (int q = 0; q < 4; q++) acc[q] = bias;
#pragma unroll
        for (int cc = 0; cc < 6; cc++) {
#pragma unroll
          for (int q = 0; q < 4; q++) acc[q] = fmaf(rlf(v, q * 8 + cc), w[cc], acc[q]);
        }
        const size_t rbase = (size_t)sg * K_ + k4;
#pragma unroll
        for (int q = 0; q < 4; q++) {
          y1[(rbase + q) * 64 + lane] = (unsigned short)rne_bf16(acc[q]);
          s0 += acc[q]; s1 = fmaf(acc[q], acc[q], s1);
        }
      }
      __syncthreads();    // protect glds before next chunk reuse
    }

    // ---- stats partials: reduce 8 waves, write slot wkr (finalize1 reads NWORK slots) ----
    spw[(wv * 2 + 0) * 64 + lane] = s0;
    spw[(wv * 2 + 1) * 64 + lane] = s1;
    __syncthreads();
    if (t < 128) {
      float p = 0.f;
#pragma unroll
      for (int ww = 0; ww < 8; ww++) p += spw[ww * 128 + t];
      partials[(size_t)t * PNB + wkr] = p;
    }
  }
}

// ---------------- fold partials -> bn scale/shift (pnb = #valid slots) ----------------
__global__ __launch_bounds__(256) void finalize_kernel(const float* __restrict__ partials,
    int cout, int pnb, const float* __restrict__ g, const float* __restrict__ be,
    float* __restrict__ bn) {
  const int c = blockIdx.x;
  const int t = threadIdx.x;
  const int lane = t & 63, wv = t >> 6;
  float s0 = 0.f, s1 = 0.f;
  for (int bb = t; bb < pnb; bb += 256) {
    s0 += partials[(size_t)c * PNB + bb];
    s1 += partials[(size_t)(cout + c) * PNB + bb];
  }
#pragma unroll
  for (int off = 32; off; off >>= 1) {
    s0 += __shfl_xor(s0, off);
    s1 += __shfl_xor(s1, off);
  }
  __shared__ float r0[4], r1[4];
  if (lane == 0) { r0[wv] = s0; r1[wv] = s1; }
  __syncthreads();
  if (t == 0) {
    double d0 = (double)r0[0] + r0[1] + r0[2] + r0[3];
    double d1 = (double)r1[0] + r1[1] + r1[2] + r1[3];
    double N = (double)ROWS;
    double mean = d0 / N;
    double var = d1 / N - mean * mean;
    double scale = (double)g[c] / sqrt(var + 1e-5);
    bn[c] = (float)scale;
    bn[cout + c] = (float)((double)be[c] - mean * scale);
  }
}

// ---------------- Layer 2 (MFMA): bn1+relu (pk) -> GEMM 64->64, 2 M-tiles/iter; permuted-K ----
__global__ __launch_bounds__(256) void layer2_kernel(
    const unsigned short* __restrict__ y1, const float* __restrict__ W,
    const float* __restrict__ bias, const float* __restrict__ bnin,
    unsigned short* __restrict__ y2, float* __restrict__ partials) {
  constexpr int NT = 4;
  const int lane = threadIdx.x & 63, wv = threadIdx.x >> 6;
  const int quad = lane >> 4, l16 = lane & 15;
  s16x8 bfrag[NT][2];
  float biasr[NT];
#pragma unroll
  for (int t = 0; t < NT; t++) {
    int n = l16 + 16 * t;
    biasr[t] = bias[n];
#pragma unroll
    for (int kc = 0; kc < 2; kc++)
#pragma unroll
      for (int j = 0; j < 8; j++)
        bfrag[t][kc][j] = rne_bf16(W[(size_t)n * 64 + kc * 32 + quad * 8 + j]);
  }
  v2f sc2[2][4], sh2[2][4];
#pragma unroll
  for (int kc = 0; kc < 2; kc++)
#pragma unroll
    for (int p = 0; p < 4; p++) {
      int k0 = kc * 32 + quad * 8 + 2 * p;
      sc2[kc][p] = (v2f){bnin[k0], bnin[k0 + 1]};
      sh2[kc][p] = (v2f){bnin[64 + k0], bnin[64 + k0 + 1]};
    }
  float s0[NT], s1[NT];
#pragma unroll
  for (int t = 0; t < NT; t++) { s0[t] = 0.f; s1[t] = 0.f; }
  const int nwaves = gridDim.x * 4;
  for (int mt = (blockIdx.x * 4 + wv) * 2; mt < ROWS / 16; mt += nwaves * 2) {
    const u32* p0 = (const u32*)(y1 + (size_t)(mt * 16 + l16) * 64 + quad * 8);
    const u32* p1 = (const u32*)(y1 + (size_t)((mt + 1) * 16 + l16) * 64 + quad * 8);
    u32 d[2][8];
#pragma unroll
    for (int q = 0; q < 4; q++) { d[0][q] = p0[q]; d[0][4 + q] = p0[16 + q]; }
#pragma unroll
    for (int q = 0; q < 4; q++) { d[1][q] = p1[q]; d[1][4 + q] = p1[16 + q]; }
    s16x8 a[2][2];
#pragma unroll
    for (int m2 = 0; m2 < 2; m2++) {
      u32* a0u = (u32*)&a[m2][0]; u32* a1u = (u32*)&a[m2][1];
#pragma unroll
      for (int q = 0; q < 4; q++) {
        a0u[q] = bnrelu_pack(d[m2][q], sc2[0][q], sh2[0][q]);
        a1u[q] = bnrelu_pack(d[m2][4 + q], sc2[1][q], sh2[1][q]);
      }
    }
    f32x4 acc[2][NT];
#pragma unroll
    for (int m2 = 0; m2 < 2; m2++)
#pragma unroll
      for (int t = 0; t < NT; t++) {
        acc[m2][t] = (f32x4){biasr[t], biasr[t], biasr[t], biasr[t]};
        acc[m2][t] = mfma16(a[m2][0], bfrag[t][0], acc[m2][t]);
        acc[m2][t] = mfma16(a[m2][1], bfrag[t][1], acc[m2][t]);
      }
#pragma unroll
    for (int m2 = 0; m2 < 2; m2++) {
#pragma unroll
      for (int r = 0; r < 4; r++) {
        u32 b01 = __builtin_amdgcn_perm(rne_bits(acc[m2][1][r]), rne_bits(acc[m2][0][r]), 0x07060302);
        u32 b23 = __builtin_amdgcn_perm(rne_bits(acc[m2][3][r]), rne_bits(acc[m2][2][r]), 0x07060302);
        int m = (mt + m2) * 16 + quad * 4 + r;
        *(uint2*)(y2 + (size_t)m * 64 + 4 * l16) = make_uint2(b01, b23);
      }
#pragma unroll
      for (int t = 0; t < NT; t++)
#pragma unroll
        for (int r = 0; r < 4; r++) {
          float v = acc[m2][t][r];
          s0[t] += v; s1[t] = fmaf(v, v, s1[t]);
        }
    }
  }
#pragma unroll
  for (int t = 0; t < NT; t++) {
    s0[t] += __shfl_xor(s0[t], 16); s0[t] += __shfl_xor(s0[t], 32);
    s1[t] += __shfl_xor(s1[t], 16); s1[t] += __shfl_xor(s1[t], 32);
  }
  __shared__ float sp[4 * 2 * 64];
  if (quad == 0) {
#pragma unroll
    for (int t = 0; t < NT; t++) {
      sp[wv * 128 + l16 + 16 * t] = s0[t];
      sp[wv * 128 + 64 + l16 + 16 * t] = s1[t];
    }
  }
  __syncthreads();
  if (threadIdx.x < 128) {
    int tt = threadIdx.x;
    float p = sp[tt] + sp[128 + tt] + sp[256 + tt] + sp[384 + tt];
    partials[(size_t)tt * PNB + blockIdx.x] = p;
  }
}

// ---------------- Fused layer3: GEMM once (permuted-K input) -> stats + per-group min/max ----
__global__ __launch_bounds__(256) void l3fused_kernel(
    const unsigned short* __restrict__ y2, const float* __restrict__ W3,
    const float* __restrict__ b3, const float* __restrict__ bn2,
    float* __restrict__ mnbuf, float* __restrict__ mxbuf,   // [b][ch][s] f32
    float* __restrict__ partials) {
  constexpr int NT = 8;
  const int lane = threadIdx.x & 63, wv = threadIdx.x >> 6;
  const int quad = lane >> 4, l16 = lane & 15;
  s16x8 bfrag[NT][2];
  float biasr[NT];
#pragma unroll
  for (int t = 0; t < NT; t++) {
    int n = l16 + 16 * t;
    biasr[t] = b3[n];
#pragma unroll
    for (int kc = 0; kc < 2; kc++)
#pragma unroll
      for (int j = 0; j < 8; j++)
        bfrag[t][kc][j] = rne_bf16(W3[(size_t)n * 64 + permc(kc * 32 + quad * 8 + j)]);
  }
  v2f sc2[2][4], sh2[2][4];
#pragma unroll
  for (int kc = 0; kc < 2; kc++)
#pragma unroll
    for (int p = 0; p < 4; p++) {
      int c0 = permc(kc * 32 + quad * 8 + 2 * p);
      int c1 = permc(kc * 32 + quad * 8 + 2 * p + 1);
      sc2[kc][p] = (v2f){bn2[c0], bn2[c1]};
      sh2[kc][p] = (v2f){bn2[64 + c0], bn2[64 + c1]};
    }
  float s0[NT], s1[NT];
#pragma unroll
  for (int t = 0; t < NT; t++) { s0[t] = 0.f; s1[t] = 0.f; }
  __shared__ float tmx[128 * 4], tmn[128 * 4];
  for (int g0 = blockIdx.x; g0 < 4096; g0 += 1024) {
    const int gq = g0 * 4 + wv;
    float mx[NT], mn[NT];
#pragma unroll
    for (int t = 0; t < NT; t++) { mx[t] = -1e30f; mn[t] = 1e30f; }
#pragma unroll
    for (int mt2 = 0; mt2 < 2; mt2++) {
      int row = gq * 32 + mt2 * 16 + l16;
      const u32* p = (const u32*)(y2 + (size_t)row * 64 + quad * 8);
      s16x8 a0, a1;
      u32* a0u = (u32*)&a0; u32* a1u = (u32*)&a1;
#pragma unroll
      for (int q = 0; q < 4; q++) {
        a0u[q] = bnrelu_pack(p[q], sc2[0][q], sh2[0][q]);
        a1u[q] = bnrelu_pack(p[16 + q], sc2[1][q], sh2[1][q]);
      }
#pragma unroll
      for (int t = 0; t < NT; t++) {
        f32x4 acc = (f32x4){biasr[t], biasr[t], biasr[t], biasr[t]};
        acc = mfma16(a0, bfrag[t][0], acc);
        acc = mfma16(a1, bfrag[t][1], acc);
#pragma unroll
        for (int r = 0; r < 4; r++) {
          float v = acc[r];
          s0[t] += v; s1[t] = fmaf(v, v, s1[t]);
          mx[t] = fmaxf(mx[t], v); mn[t] = fminf(mn[t], v);
        }
      }
    }
#pragma unroll
    for (int t = 0; t < NT; t++) {
      mx[t] = fmaxf(mx[t], __shfl_xor(mx[t], 16));
      mx[t] = fmaxf(mx[t], __shfl_xor(mx[t], 32));
      mn[t] = fminf(mn[t], __shfl_xor(mn[t], 16));
      mn[t] = fminf(mn[t], __shfl_xor(mn[t], 32));
    }
    if (quad == 0) {
#pragma unroll
      for (int t = 0; t < NT; t++) {
        tmx[(l16 + 16 * t) * 4 + wv] = mx[t];
        tmn[(l16 + 16 * t) * 4 + wv] = mn[t];
      }
    }
    __syncthreads();
    if (threadIdx.x < 128) {
      int b = g0 >> 8;
      int s0i = (g0 & 255) * 4;
      size_t o = ((size_t)b * 128 + threadIdx.x) * 1024 + s0i;
      *(float4*)&mxbuf[o] = *(float4*)&tmx[threadIdx.x * 4];
      *(float4*)&mnbuf[o] = *(float4*)&tmn[threadIdx.x * 4];
    }
    __syncthreads();
  }
#pragma unroll
  for (int t = 0; t < NT; t++) {
    s0[t] += __shfl_xor(s0[t], 16); s0[t] += __shfl_xor(s0[t], 32);
    s1[t] += __shfl_xor(s1[t], 16); s1[t] += __shfl_xor(s1[t], 32);
  }
  __shared__ float sp[4 * 2 * 128];
  if (quad == 0) {
#pragma unroll
    for (int t = 0; t < NT; t++) {
      sp[wv * 256 + l16 + 16 * t] = s0[t];
      sp[wv * 256 + 128 + l16 + 16 * t] = s1[t];
    }
  }
  __syncthreads();
  {
    int tt = threadIdx.x;
    float p = sp[tt] + sp[256 + tt] + sp[512 + tt] + sp[768 + tt];
    partials[(size_t)tt * PNB + blockIdx.x] = p;
  }
}

// ---------------- fused finalize3 + apply: each block covers exactly ONE channel ------------
__global__ __launch_bounds__(256) void l3final_kernel(
    const float* __restrict__ partials, const float* __restrict__ g,
    const float* __restrict__ be, const float* __restrict__ mnbuf,
    const float* __restrict__ mxbuf, float* __restrict__ out1) {
  const int t = threadIdx.x;
  const int ch = (blockIdx.x >> 2) & 127;
  const int lane = t & 63, wv = t >> 6;
  float s0 = 0.f, s1 = 0.f;
  for (int bb = t; bb < PNB; bb += 256) {
    s0 += partials[(size_t)ch * PNB + bb];
    s1 += partials[(size_t)(128 + ch) * PNB + bb];
  }
#pragma unroll
  for (int off = 32; off; off >>= 1) {
    s0 += __shfl_xor(s0, off);
    s1 += __shfl_xor(s1, off);
  }
  __shared__ float r0[4], r1[4];
  __shared__ float bnsh[2];
  if (lane == 0) { r0[wv] = s0; r1[wv] = s1; }
  __syncthreads();
  if (t == 0) {
    double d0 = (double)r0[0] + r0[1] + r0[2] + r0[3];
    double d1 = (double)r1[0] + r1[1] + r1[2] + r1[3];
    double N = (double)ROWS;
    double mean = d0 / N;
    double var = d1 / N - mean * mean;
    double scale = (double)g[ch] / sqrt(var + 1e-5);
    bnsh[0] = (float)scale;
    bnsh[1] = (float)((double)be[ch] - mean * scale);
  }
  __syncthreads();
  float s = bnsh[0], h = bnsh[1];
  int i = blockIdx.x * 256 + t;
  float v = (s > 0.f) ? mxbuf[i] : mnbuf[i];
  out1[i] = fmaxf(fmaf(v, s, h), 0.f);
}

extern "C" void kernel_launch(void* const* d_in, const int* in_sizes, int n_in,
                              void* d_out, int out_size, void* d_ws, size_t ws_size,
                              hipStream_t stream) {
  const float* xyz = (const float*)d_in[0];
  const float* pts = (const float*)d_in[1];
  const float* W1 = (const float*)d_in[2],  *b1 = (const float*)d_in[3];
  const float* g1 = (const float*)d_in[4],  *be1 = (const float*)d_in[5];
  const float* W2 = (const float*)d_in[6],  *b2 = (const float*)d_in[7];
  const float* g2 = (const float*)d_in[8],  *be2 = (const float*)d_in[9];
  const float* W3 = (const float*)d_in[10], *b3 = (const float*)d_in[11];
  const float* g3 = (const float*)d_in[12], *be3 = (const float*)d_in[13];
  float* out0 = (float*)d_out;                 // xyz_query_pc [16,3,1024]
  float* out1 = out0 + B_ * 3 * S_;            // new_points   [16,128,1024]

  char* ws = (char*)d_ws;
  float* new_xyz  = (float*)(ws);
  float* bn1      = (float*)(ws + 196608);
  float* bn2      = bn1 + 128;
  int*   prog     = (int*)(ws + 198656);                           // 16 ints (old gidx spot)
  float* partials = (float*)(ws + 2295808);
  unsigned short* y1 = (unsigned short*)(ws + 4392960);            // 64 MB bf16
  unsigned short* y2 = (unsigned short*)(ws + 4392960 + 67108864); // 64 MB bf16 (K-permuted)
  float* mnbuf = (float*)(ws + 4392960);                           // reuse y1 space
  float* mxbuf = (float*)(ws + 4392960 + 8388608);

  hipMemsetAsync(prog, 0, 64, stream);   // reset progress flags each replay
  head_kernel<<<B_ + NWORK, 512, 0, stream>>>(xyz, pts, W1, b1, out0, new_xyz, prog, y1, partials);
  finalize_kernel<<<64, 256, 0, stream>>>(partials, 64, NWORK, g1, be1, bn1);
  layer2_kernel<<<PNB, 256, 0, stream>>>(y1, W2, b2, bn1, y2, partials);
  finalize_kernel<<<64, 256, 0, stream>>>(partials, 64, PNB, g2, be2, bn2);
  l3fused_kernel<<<PNB, 256, 0, stream>>>(y2, W3, b3, bn2, mnbuf, mxbuf, partials);
  l3final_kernel<<<8192, 256, 0, stream>>>(partials, g3, be3, mnbuf, mxbuf, out1);
}

// Round 3
// 847.713 us; speedup vs baseline: 1.0852x; 1.0504x over previous
//
#include <hip/hip_runtime.h>

#pragma clang fp contract(off)

#define NPT 4096
#define B_ 16
#define S_ 1024
#define K_ 32
#define ROWS (B_*S_*K_)   // 524288
#define PNB 1024          // partial-stats blocks (layer kernels' grid)
#define NWORK 240         // worker blocks in head kernel (grid 256 = 16 fps + 240, 1 blk/CU)
#define NCHUNK 512        // 16 batches * 32 chunks of 32 queries

typedef float v2f __attribute__((ext_vector_type(2)));
typedef unsigned int u32;
typedef unsigned long long u64;
typedef __attribute__((ext_vector_type(8))) short s16x8;
typedef __attribute__((ext_vector_type(4))) float f32x4;

__device__ __forceinline__ float rlf(float v, int l) {
  return __uint_as_float(__builtin_amdgcn_readlane(__float_as_uint(v), l));
}

__device__ __forceinline__ short rne_bf16(float x) {
  u32 b = __float_as_uint(x);
  b += 0x7FFFu + ((b >> 16) & 1u);
  return (short)(b >> 16);
}
__device__ __forceinline__ u32 rne_bits(float x) {   // rounded bits, result in high 16
  u32 b = __float_as_uint(x);
  return b + 0x7FFFu + ((b >> 16) & 1u);
}

__device__ __forceinline__ f32x4 mfma16(s16x8 a, s16x8 b, f32x4 c) {
  return __builtin_amdgcn_mfma_f32_16x16x32_bf16(a, b, c, 0, 0, 0);
}

// stored-position -> original channel permutation for y2 (layer2 fast stores)
__device__ __forceinline__ int permc(int p) { return ((p & 3) << 4) | (p >> 2); }

// relaxed agent atomics = sc1 load/store at the MALL coherence point.
// NO buffer_inv / buffer_wbl2 (R2 lesson: acquire/release at agent scope lower to full-L2
// invalidate / writeback on gfx950 — the release wbl2 on the FPS critical path and the
// per-poll inv in worker spins caused ~1 GB of L2 refetch and ~110us of FPS stall).
__device__ __forceinline__ void st_sc1(float* p, float v) {
  __hip_atomic_store(p, v, __ATOMIC_RELAXED, __HIP_MEMORY_SCOPE_AGENT);
}
__device__ __forceinline__ float ld_sc1(const float* p) {
  return __hip_atomic_load((float*)p, __ATOMIC_RELAXED, __HIP_MEMORY_SCOPE_AGENT);
}

// BN+relu+RNE-pack for a bf16 pair held in one dword. Bit-exact vs scalar path.
__device__ __forceinline__ u32 bnrelu_pack(u32 d, v2f sc, v2f sh) {
  v2f a;
  a.x = __uint_as_float(d << 16);
  a.y = __uint_as_float(d & 0xFFFF0000u);
  v2f z = __builtin_elementwise_fma(a, sc, sh);
  z = __builtin_elementwise_max(z, (v2f){0.f, 0.f});
  u32 zx = rne_bits(z.x), zy = rne_bits(z.y);
  return __builtin_amdgcn_perm(zy, zx, 0x07060302);   // {zx.hi16, zy.hi16}
}

template <int CTRL>
__device__ __forceinline__ u64 dpp_u64(u64 x) {
  int lo = (int)(u32)x, hi = (int)(u32)(x >> 32);
  lo = __builtin_amdgcn_update_dpp(lo, lo, CTRL, 0xF, 0xF, false);
  hi = __builtin_amdgcn_update_dpp(hi, hi, CTRL, 0xF, 0xF, false);
  return ((u64)(u32)hi << 32) | (u32)lo;
}
// full-wave f64 max -> lane 63. Keys are positive doubles => f64 order == u64 order.
__device__ __forceinline__ double wave_max_f64(double k) {
  k = fmax(k, __longlong_as_double((long long)dpp_u64<0x111>((u64)__double_as_longlong(k))));
  k = fmax(k, __longlong_as_double((long long)dpp_u64<0x112>((u64)__double_as_longlong(k))));
  k = fmax(k, __longlong_as_double((long long)dpp_u64<0x114>((u64)__double_as_longlong(k))));
  k = fmax(k, __longlong_as_double((long long)dpp_u64<0x118>((u64)__double_as_longlong(k))));
  k = fmax(k, __longlong_as_double((long long)dpp_u64<0x142>((u64)__double_as_longlong(k))));
  k = fmax(k, __longlong_as_double((long long)dpp_u64<0x143>((u64)__double_as_longlong(k))));
  return k;
}

__device__ __forceinline__ double mkkey(float d, u32 lo) {
  return __longlong_as_double((long long)(((u64)__float_as_uint(d) << 32) | lo));
}

// ---------------- HEAD: fused FPS + ball-query + layer1 ----------------
// Blocks 0..15: FPS, one block per batch (FINAL R5/R8 structure — DO NOT retune the core
// loop). Publish: wave 1 stores 32 centroid rows as sc1 (relaxed-agent) stores every 32
// iters, then raw s_waitcnt vmcnt(0) + sc1 flag store (hand-rolled release WITHOUT wbl2:
// sc1 store acks imply MALL visibility, so vmcnt(0)-then-flag is a sound release).
// LDS padded >81920B to force 1 block/CU (R1 lesson): FPS must not share SIMDs with
// worker waves. 256 blocks / 256 CUs.
// Blocks 16..255: workers. Spin on prog[b] with relaxed sc1 loads (NO buffer_inv), then
// sc1-load the chunk's 32 query rows ONCE into LDS (plain loads could hit stale L2 lines
// covering ~10 adjacent 12B rows). xyz/pts/weights are pre-launch data -> cached loads OK.
// Correctness never depends on co-residency: FPS never waits on workers; worker spins are
// bounded; if workers serialize after FPS they still read prog=final and compute correctly.
__global__ __launch_bounds__(512, 4) void head_kernel(
    const float* __restrict__ xyz, const float* __restrict__ pts,
    const float* __restrict__ W1, const float* __restrict__ b1,
    float* __restrict__ out0, float* __restrict__ new_xyz,
    int* __restrict__ prog, unsigned short* __restrict__ y1,
    float* __restrict__ partials) {
  __shared__ float4 spt[NPT + 520]; // 64KB + 8320B pad -> LDS > 81920B => 1 block/CU
  __shared__ u64 skey[3];           // fps only
  __shared__ int sfar[S_];          // fps: selection journal; worker: gidx scratch (1024 ints)
  __shared__ float spw[8 * 2 * 64]; // worker stats reduce
  __shared__ float snq[8][12];      // worker: per-wave query coords (sc1-loaded once/chunk)
  const int bid = blockIdx.x;
  const int t = threadIdx.x;
  const int lane = t & 63;

  if (bid < B_) {
    // ================= FPS =================
    const int b = bid;
    const float* xb = xyz + (size_t)b * 3 * NPT;
#pragma unroll
    for (int j = 0; j < 8; j++) {
      int m = t + j * 512;
      spt[m] = make_float4(xb[m], xb[NPT + m], xb[2 * NPT + m], 0.f);
    }
    if (t < 3) skey[t] = 0ull;
    const float4* xb4 = (const float4*)xb;
    float4 X0 = xb4[t * 2], X1 = xb4[t * 2 + 1];
    float4 Y0 = xb4[NPT / 4 + t * 2], Y1 = xb4[NPT / 4 + t * 2 + 1];
    float4 Z0 = xb4[2 * NPT / 4 + t * 2], Z1 = xb4[2 * NPT / 4 + t * 2 + 1];
    v2f px[4], py[4], pz[4], ds[4];
    px[0] = (v2f){X0.x, X0.y}; px[1] = (v2f){X0.z, X0.w}; px[2] = (v2f){X1.x, X1.y}; px[3] = (v2f){X1.z, X1.w};
    py[0] = (v2f){Y0.x, Y0.y}; py[1] = (v2f){Y0.z, Y0.w}; py[2] = (v2f){Y1.x, Y1.y}; py[3] = (v2f){Y1.z, Y1.w};
    pz[0] = (v2f){Z0.x, Z0.y}; pz[1] = (v2f){Z0.z, Z0.w}; pz[2] = (v2f){Z1.x, Z1.y}; pz[3] = (v2f){Z1.z, Z1.w};
    const int base = t * 8;
    u32 lo[8];
#pragma unroll
    for (int i = 0; i < 8; i++) lo[i] = ~(u32)(base + i);
#pragma unroll
    for (int j = 0; j < 4; j++) ds[j] = (v2f){1e10f, 1e10f};
    __syncthreads();
    int far = 0, slot = 0;
    for (int it = 0; it < S_; ++it) {
      if (t == 0) sfar[it] = far;
      // bulk publish of centroid rows [it-32, it) on WAVE 1 (keeps wave 0's serial path
      // lean). sfar[pit] for pit<it all written pre-barrier in earlier iters -> visible.
      if ((it & 31) == 0 && it != 0) {
        if (t >= 64 && t < 96) {
          int pit = it - 32 + (t - 64);
          float4 p = spt[sfar[pit]];
          size_t o = ((size_t)b * S_ + pit) * 3;
          st_sc1(&new_xyz[o + 0], p.x);
          st_sc1(&new_xyz[o + 1], p.y);
          st_sc1(&new_xyz[o + 2], p.z);
        }
        if (t == 64) {
          asm volatile("s_waitcnt vmcnt(0)" ::: "memory");  // sc1 acks = MALL-visible
          __hip_atomic_store(&prog[b], it, __ATOMIC_RELAXED, __HIP_MEMORY_SCOPE_AGENT);
        }
      }
      float4 c = spt[far];
      v2f cx = (v2f){c.x, c.x}, cy = (v2f){c.y, c.y}, cz = (v2f){c.z, c.z};
#pragma unroll
      for (int j = 0; j < 4; j++) {
        // exact ref op order per element: ((dx*dx + dy*dy) + dz*dz), contraction OFF
        v2f dx = px[j] - cx, dy = py[j] - cy, dz = pz[j] - cz;
        v2f s = dx * dx + dy * dy;
        v2f d = s + dz * dz;
        v2f nd;
        nd.x = fminf(ds[j].x, d.x);
        nd.y = fminf(ds[j].y, d.y);
        ds[j] = nd;
      }
      // f64 sortable keys: max dist, tie -> min index (via ~idx in low word)
      double k = fmax(fmax(fmax(mkkey(ds[0].x, lo[0]), mkkey(ds[0].y, lo[1])),
                           fmax(mkkey(ds[1].x, lo[2]), mkkey(ds[1].y, lo[3]))),
                      fmax(fmax(mkkey(ds[2].x, lo[4]), mkkey(ds[2].y, lo[5])),
                           fmax(mkkey(ds[3].x, lo[6]), mkkey(ds[3].y, lo[7]))));
      k = wave_max_f64(k);
      if (lane == 63) atomicMax(&skey[slot], (u64)__double_as_longlong(k));
      __syncthreads();
      u64 kk = skey[slot];
      if (t == 0) skey[slot == 0 ? 2 : slot - 1] = 0ull;  // reset slot (it+2)%3: safe post-barrier
      far = (int)(~(u32)kk);
      slot = (slot == 2) ? 0 : slot + 1;
    }
    __syncthreads();
    // final publish: rows 992..1023, then prog=1024
    if (t < 32) {
      int pit = 992 + t;
      float4 p = spt[sfar[pit]];
      size_t o = ((size_t)b * S_ + pit) * 3;
      st_sc1(&new_xyz[o + 0], p.x);
      st_sc1(&new_xyz[o + 1], p.y);
      st_sc1(&new_xyz[o + 2], p.z);
    }
    if (t == 0) {
      asm volatile("s_waitcnt vmcnt(0)" ::: "memory");
      __hip_atomic_store(&prog[b], S_, __ATOMIC_RELAXED, __HIP_MEMORY_SCOPE_AGENT);
    }
    // coalesced writeback of out0
#pragma unroll
    for (int j = 0; j < 2; j++) {
      int it = t + j * 512;
      float4 p = spt[sfar[it]];
      out0[(b * 3 + 0) * S_ + it] = p.x;
      out0[(b * 3 + 1) * S_ + it] = p.y;
      out0[(b * 3 + 2) * S_ + it] = p.z;
    }
  } else {
    // ================= WORKER: ballq + layer1 =================
    const int wv = t >> 6;
    const int grp = lane >> 3;          // 0..7; groups 0..3 gather for rows A..D
    const int gc = lane & 7;            // channel slot within group (0..5 used)
    const int wkr = bid - B_;
    float w[6];
#pragma unroll
    for (int cc = 0; cc < 6; cc++) w[cc] = W1[lane * 6 + cc];
    const float bias = b1[lane];
    float s0 = 0.f, s1 = 0.f;
    int* glds = sfar;                   // 1024 ints: [wave][4 queries][32 idx]

    for (int cid = wkr; cid < NCHUNK; cid += NWORK) {
      const int b = cid & 15, cch = cid >> 4;
      if (t == 0) {
        const int tgt = (cch + 1) * 32;
        int spins = 0;
        while (__hip_atomic_load(&prog[b], __ATOMIC_RELAXED, __HIP_MEMORY_SCOPE_AGENT) < tgt) {
          __builtin_amdgcn_s_sleep(8);
          if (++spins > (1 << 20)) break;   // fail-safe: never hang the device
        }
      }
      __syncthreads();

      // ---- ball query: 4 queries per wave, shared coordinate loads (bit-exact vs ballq) ----
      const float* xb = xyz + (size_t)b * 3 * NPT;
      const int q0 = cch * 32 + wv * 4;         // local query base in batch
      const int sg0 = b * 1024 + q0;            // global query base
      // sc1-load this wave's 12 query floats once (lanes 0..11), stage via LDS (wave-sync)
      if (lane < 12)
        snq[wv][lane] = ld_sc1(&new_xyz[(size_t)sg0 * 3 + lane]);
      asm volatile("s_waitcnt vmcnt(0) lgkmcnt(0)" ::: "memory");
      float qx[4], qy[4], qz[4];
      int cnt[4], fi[4];
#pragma unroll
      for (int j = 0; j < 4; j++) {
        qx[j] = snq[wv][j * 3 + 0];
        qy[j] = snq[wv][j * 3 + 1];
        qz[j] = snq[wv][j * 3 + 2];
        cnt[j] = 0; fi[j] = 0x7fffffff;
      }
      const float R2 = (float)(0.4 * 0.4);
      int* gl = glds + wv * 4 * K_;
      for (int c0 = 0; c0 < NPT; c0 += 64) {
        if (cnt[0] >= K_ && cnt[1] >= K_ && cnt[2] >= K_ && cnt[3] >= K_) break;
        int n = c0 + lane;
        float x = xb[n], y = xb[NPT + n], z = xb[2 * NPT + n];
#pragma unroll
        for (int j = 0; j < 4; j++) {
          if (cnt[j] < K_) {                    // wave-uniform guard: identical writes vs ballq
            float dx = __fadd_rn(qx[j], -x);
            float dy = __fadd_rn(qy[j], -y);
            float dz = __fadd_rn(qz[j], -z);
            float sq = __fadd_rn(__fadd_rn(__fmul_rn(dx, dx), __fmul_rn(dy, dy)), __fmul_rn(dz, dz));
            bool inr = !(sq > R2);
            unsigned long long m = __ballot(inr);
            if (inr) {
              int pos = cnt[j] + (int)__popcll(m & ((1ull << lane) - 1ull));
              if (pos < K_) gl[j * K_ + pos] = n;
            }
            if (fi[j] == 0x7fffffff && m) fi[j] = c0 + (int)__builtin_ctzll(m);
            cnt[j] += (int)__popcll(m);
          }
        }
      }
#pragma unroll
      for (int j = 0; j < 4; j++)
        if (lane >= cnt[j] && lane < K_) gl[j * K_ + lane] = fi[j];
      __syncthreads();

      // ---- layer1: 4 queries x 32 rows, 4 rows per iter (bit-exact vs layer1_kernel) ----
      // new_xyz subtraction uses snq (same published values; sc1-staged -> no stale L2)
      for (int it = 0; it < 32; ++it) {
        const int j = it >> 3, k4 = (it & 7) * 4;
        const int sg = sg0 + j;                 // global query (== rr>>5)
        float v = 0.f;
        if (grp < 4 && gc < 6) {
          int gi = gl[j * K_ + k4 + grp];
          if (gc < 3) v = xyz[((size_t)b * 3 + gc) * NPT + gi] - snq[wv][j * 3 + gc];
          else        v = pts[((size_t)b * 3 + (gc - 3)) * NPT + gi];
        }
        float acc[4];
#pragma unroll
        for (int q = 0; q < 4; q++) acc[q] = bias;
#pragma unroll
        for (int cc = 0; cc < 6; cc++) {
#pragma unroll
          for (int q = 0; q < 4; q++) acc[q] = fmaf(rlf(v, q * 8 + cc), w[cc], acc[q]);
        }
        const size_t rbase = (size_t)sg * K_ + k4;
#pragma unroll
        for (int q = 0; q < 4; q++) {
          y1[(rbase + q) * 64 + lane] = (unsigned short)rne_bf16(acc[q]);
          s0 += acc[q]; s1 = fmaf(acc[q], acc[q], s1);
        }
      }
      __syncthreads();    // protect glds before next chunk reuse
    }

    // ---- stats partials: reduce 8 waves, write slot wkr (finalize1 reads NWORK slots) ----
    spw[(wv * 2 + 0) * 64 + lane] = s0;
    spw[(wv * 2 + 1) * 64 + lane] = s1;
    __syncthreads();
    if (t < 128) {
      float p = 0.f;
#pragma unroll
      for (int ww = 0; ww < 8; ww++) p += spw[ww * 128 + t];
      partials[(size_t)t * PNB + wkr] = p;
    }
  }
}

// ---------------- fold partials -> bn scale/shift (pnb = #valid slots) ----------------
__global__ __launch_bounds__(256) void finalize_kernel(const float* __restrict__ partials,
    int cout, int pnb, const float* __restrict__ g, const float* __restrict__ be,
    float* __restrict__ bn) {
  const int c = blockIdx.x;
  const int t = threadIdx.x;
  const int lane = t & 63, wv = t >> 6;
  float s0 = 0.f, s1 = 0.f;
  for (int bb = t; bb < pnb; bb += 256) {
    s0 += partials[(size_t)c * PNB + bb];
    s1 += partials[(size_t)(cout + c) * PNB + bb];
  }
#pragma unroll
  for (int off = 32; off; off >>= 1) {
    s0 += __shfl_xor(s0, off);
    s1 += __shfl_xor(s1, off);
  }
  __shared__ float r0[4], r1[4];
  if (lane == 0) { r0[wv] = s0; r1[wv] = s1; }
  __syncthreads();
  if (t == 0) {
    double d0 = (double)r0[0] + r0[1] + r0[2] + r0[3];
    double d1 = (double)r1[0] + r1[1] + r1[2] + r1[3];
    double N = (double)ROWS;
    double mean = d0 / N;
    double var = d1 / N - mean * mean;
    double scale = (double)g[c] / sqrt(var + 1e-5);
    bn[c] = (float)scale;
    bn[cout + c] = (float)((double)be[c] - mean * scale);
  }
}

// ---------------- Layer 2 (MFMA): bn1+relu (pk) -> GEMM 64->64, 2 M-tiles/iter; permuted-K ----
__global__ __launch_bounds__(256) void layer2_kernel(
    const unsigned short* __restrict__ y1, const float* __restrict__ W,
    const float* __restrict__ bias, const float* __restrict__ bnin,
    unsigned short* __restrict__ y2, float* __restrict__ partials) {
  constexpr int NT = 4;
  const int lane = threadIdx.x & 63, wv = threadIdx.x >> 6;
  const int quad = lane >> 4, l16 = lane & 15;
  s16x8 bfrag[NT][2];
  float biasr[NT];
#pragma unroll
  for (int t = 0; t < NT; t++) {
    int n = l16 + 16 * t;
    biasr[t] = bias[n];
#pragma unroll
    for (int kc = 0; kc < 2; kc++)
#pragma unroll
      for (int j = 0; j < 8; j++)
        bfrag[t][kc][j] = rne_bf16(W[(size_t)n * 64 + kc * 32 + quad * 8 + j]);
  }
  v2f sc2[2][4], sh2[2][4];
#pragma unroll
  for (int kc = 0; kc < 2; kc++)
#pragma unroll
    for (int p = 0; p < 4; p++) {
      int k0 = kc * 32 + quad * 8 + 2 * p;
      sc2[kc][p] = (v2f){bnin[k0], bnin[k0 + 1]};
      sh2[kc][p] = (v2f){bnin[64 + k0], bnin[64 + k0 + 1]};
    }
  float s0[NT], s1[NT];
#pragma unroll
  for (int t = 0; t < NT; t++) { s0[t] = 0.f; s1[t] = 0.f; }
  const int nwaves = gridDim.x * 4;
  for (int mt = (blockIdx.x * 4 + wv) * 2; mt < ROWS / 16; mt += nwaves * 2) {
    const u32* p0 = (const u32*)(y1 + (size_t)(mt * 16 + l16) * 64 + quad * 8);
    const u32* p1 = (const u32*)(y1 + (size_t)((mt + 1) * 16 + l16) * 64 + quad * 8);
    u32 d[2][8];
#pragma unroll
    for (int q = 0; q < 4; q++) { d[0][q] = p0[q]; d[0][4 + q] = p0[16 + q]; }
#pragma unroll
    for (int q = 0; q < 4; q++) { d[1][q] = p1[q]; d[1][4 + q] = p1[16 + q]; }
    s16x8 a[2][2];
#pragma unroll
    for (int m2 = 0; m2 < 2; m2++) {
      u32* a0u = (u32*)&a[m2][0]; u32* a1u = (u32*)&a[m2][1];
#pragma unroll
      for (int q = 0; q < 4; q++) {
        a0u[q] = bnrelu_pack(d[m2][q], sc2[0][q], sh2[0][q]);
        a1u[q] = bnrelu_pack(d[m2][4 + q], sc2[1][q], sh2[1][q]);
      }
    }
    f32x4 acc[2][NT];
#pragma unroll
    for (int m2 = 0; m2 < 2; m2++)
#pragma unroll
      for (int t = 0; t < NT; t++) {
        acc[m2][t] = (f32x4){biasr[t], biasr[t], biasr[t], biasr[t]};
        acc[m2][t] = mfma16(a[m2][0], bfrag[t][0], acc[m2][t]);
        acc[m2][t] = mfma16(a[m2][1], bfrag[t][1], acc[m2][t]);
      }
#pragma unroll
    for (int m2 = 0; m2 < 2; m2++) {
#pragma unroll
      for (int r = 0; r < 4; r++) {
        u32 b01 = __builtin_amdgcn_perm(rne_bits(acc[m2][1][r]), rne_bits(acc[m2][0][r]), 0x07060302);
        u32 b23 = __builtin_amdgcn_perm(rne_bits(acc[m2][3][r]), rne_bits(acc[m2][2][r]), 0x07060302);
        int m = (mt + m2) * 16 + quad * 4 + r;
        *(uint2*)(y2 + (size_t)m * 64 + 4 * l16) = make_uint2(b01, b23);
      }
#pragma unroll
      for (int t = 0; t < NT; t++)
#pragma unroll
        for (int r = 0; r < 4; r++) {
          float v = acc[m2][t][r];
          s0[t] += v; s1[t] = fmaf(v, v, s1[t]);
        }
    }
  }
#pragma unroll
  for (int t = 0; t < NT; t++) {
    s0[t] += __shfl_xor(s0[t], 16); s0[t] += __shfl_xor(s0[t], 32);
    s1[t] += __shfl_xor(s1[t], 16); s1[t] += __shfl_xor(s1[t], 32);
  }
  __shared__ float sp[4 * 2 * 64];
  if (quad == 0) {
#pragma unroll
    for (int t = 0; t < NT; t++) {
      sp[wv * 128 + l16 + 16 * t] = s0[t];
      sp[wv * 128 + 64 + l16 + 16 * t] = s1[t];
    }
  }
  __syncthreads();
  if (threadIdx.x < 128) {
    int tt = threadIdx.x;
    float p = sp[tt] + sp[128 + tt] + sp[256 + tt] + sp[384 + tt];
    partials[(size_t)tt * PNB + blockIdx.x] = p;
  }
}

// ---------------- Fused layer3: GEMM once (permuted-K input) -> stats + per-group min/max ----
__global__ __launch_bounds__(256) void l3fused_kernel(
    const unsigned short* __restrict__ y2, const float* __restrict__ W3,
    const float* __restrict__ b3, const float* __restrict__ bn2,
    float* __restrict__ mnbuf, float* __restrict__ mxbuf,   // [b][ch][s] f32
    float* __restrict__ partials) {
  constexpr int NT = 8;
  const int lane = threadIdx.x & 63, wv = threadIdx.x >> 6;
  const int quad = lane >> 4, l16 = lane & 15;
  s16x8 bfrag[NT][2];
  float biasr[NT];
#pragma unroll
  for (int t = 0; t < NT; t++) {
    int n = l16 + 16 * t;
    biasr[t] = b3[n];
#pragma unroll
    for (int kc = 0; kc < 2; kc++)
#pragma unroll
      for (int j = 0; j < 8; j++)
        bfrag[t][kc][j] = rne_bf16(W3[(size_t)n * 64 + permc(kc * 32 + quad * 8 + j)]);
  }
  v2f sc2[2][4], sh2[2][4];
#pragma unroll
  for (int kc = 0; kc < 2; kc++)
#pragma unroll
    for (int p = 0; p < 4; p++) {
      int c0 = permc(kc * 32 + quad * 8 + 2 * p);
      int c1 = permc(kc * 32 + quad * 8 + 2 * p + 1);
      sc2[kc][p] = (v2f){bn2[c0], bn2[c1]};
      sh2[kc][p] = (v2f){bn2[64 + c0], bn2[64 + c1]};
    }
  float s0[NT], s1[NT];
#pragma unroll
  for (int t = 0; t < NT; t++) { s0[t] = 0.f; s1[t] = 0.f; }
  __shared__ float tmx[128 * 4], tmn[128 * 4];
  for (int g0 = blockIdx.x; g0 < 4096; g0 += 1024) {
    const int gq = g0 * 4 + wv;
    float mx[NT], mn[NT];
#pragma unroll
    for (int t = 0; t < NT; t++) { mx[t] = -1e30f; mn[t] = 1e30f; }
#pragma unroll
    for (int mt2 = 0; mt2 < 2; mt2++) {
      int row = gq * 32 + mt2 * 16 + l16;
      const u32* p = (const u32*)(y2 + (size_t)row * 64 + quad * 8);
      s16x8 a0, a1;
      u32* a0u = (u32*)&a0; u32* a1u = (u32*)&a1;
#pragma unroll
      for (int q = 0; q < 4; q++) {
        a0u[q] = bnrelu_pack(p[q], sc2[0][q], sh2[0][q]);
        a1u[q] = bnrelu_pack(p[16 + q], sc2[1][q], sh2[1][q]);
      }
#pragma unroll
      for (int t = 0; t < NT; t++) {
        f32x4 acc = (f32x4){biasr[t], biasr[t], biasr[t], biasr[t]};
        acc = mfma16(a0, bfrag[t][0], acc);
        acc = mfma16(a1, bfrag[t][1], acc);
#pragma unroll
        for (int r = 0; r < 4; r++) {
          float v = acc[r];
          s0[t] += v; s1[t] = fmaf(v, v, s1[t]);
          mx[t] = fmaxf(mx[t], v); mn[t] = fminf(mn[t], v);
        }
      }
    }
#pragma unroll
    for (int t = 0; t < NT; t++) {
      mx[t] = fmaxf(mx[t], __shfl_xor(mx[t], 16));
      mx[t] = fmaxf(mx[t], __shfl_xor(mx[t], 32));
      mn[t] = fminf(mn[t], __shfl_xor(mn[t], 16));
      mn[t] = fminf(mn[t], __shfl_xor(mn[t], 32));
    }
    if (quad == 0) {
#pragma unroll
      for (int t = 0; t < NT; t++) {
        tmx[(l16 + 16 * t) * 4 + wv] = mx[t];
        tmn[(l16 + 16 * t) * 4 + wv] = mn[t];
      }
    }
    __syncthreads();
    if (threadIdx.x < 128) {
      int b = g0 >> 8;
      int s0i = (g0 & 255) * 4;
      size_t o = ((size_t)b * 128 + threadIdx.x) * 1024 + s0i;
      *(float4*)&mxbuf[o] = *(float4*)&tmx[threadIdx.x * 4];
      *(float4*)&mnbuf[o] = *(float4*)&tmn[threadIdx.x * 4];
    }
    __syncthreads();
  }
#pragma unroll
  for (int t = 0; t < NT; t++) {
    s0[t] += __shfl_xor(s0[t], 16); s0[t] += __shfl_xor(s0[t], 32);
    s1[t] += __shfl_xor(s1[t], 16); s1[t] += __shfl_xor(s1[t], 32);
  }
  __shared__ float sp[4 * 2 * 128];
  if (quad == 0) {
#pragma unroll
    for (int t = 0; t < NT; t++) {
      sp[wv * 256 + l16 + 16 * t] = s0[t];
      sp[wv * 256 + 128 + l16 + 16 * t] = s1[t];
    }
  }
  __syncthreads();
  {
    int tt = threadIdx.x;
    float p = sp[tt] + sp[256 + tt] + sp[512 + tt] + sp[768 + tt];
    partials[(size_t)tt * PNB + blockIdx.x] = p;
  }
}

// ---------------- fused finalize3 + apply: each block covers exactly ONE channel ------------
__global__ __launch_bounds__(256) void l3final_kernel(
    const float* __restrict__ partials, const float* __restrict__ g,
    const float* __restrict__ be, const float* __restrict__ mnbuf,
    const float* __restrict__ mxbuf, float* __restrict__ out1) {
  const int t = threadIdx.x;
  const int ch = (blockIdx.x >> 2) & 127;
  const int lane = t & 63, wv = t >> 6;
  float s0 = 0.f, s1 = 0.f;
  for (int bb = t; bb < PNB; bb += 256) {
    s0 += partials[(size_t)ch * PNB + bb];
    s1 += partials[(size_t)(128 + ch) * PNB + bb];
  }
#pragma unroll
  for (int off = 32; off; off >>= 1) {
    s0 += __shfl_xor(s0, off);
    s1 += __shfl_xor(s1, off);
  }
  __shared__ float r0[4], r1[4];
  __shared__ float bnsh[2];
  if (lane == 0) { r0[wv] = s0; r1[wv] = s1; }
  __syncthreads();
  if (t == 0) {
    double d0 = (double)r0[0] + r0[1] + r0[2] + r0[3];
    double d1 = (double)r1[0] + r1[1] + r1[2] + r1[3];
    double N = (double)ROWS;
    double mean = d0 / N;
    double var = d1 / N - mean * mean;
    double scale = (double)g[ch] / sqrt(var + 1e-5);
    bnsh[0] = (float)scale;
    bnsh[1] = (float)((double)be[ch] - mean * scale);
  }
  __syncthreads();
  float s = bnsh[0], h = bnsh[1];
  int i = blockIdx.x * 256 + t;
  float v = (s > 0.f) ? mxbuf[i] : mnbuf[i];
  out1[i] = fmaxf(fmaf(v, s, h), 0.f);
}

extern "C" void kernel_launch(void* const* d_in, const int* in_sizes, int n_in,
                              void* d_out, int out_size, void* d_ws, size_t ws_size,
                              hipStream_t stream) {
  const float* xyz = (const float*)d_in[0];
  const float* pts = (const float*)d_in[1];
  const float* W1 = (const float*)d_in[2],  *b1 = (const float*)d_in[3];
  const float* g1 = (const float*)d_in[4],  *be1 = (const float*)d_in[5];
  const float* W2 = (const float*)d_in[6],  *b2 = (const float*)d_in[7];
  const float* g2 = (const float*)d_in[8],  *be2 = (const float*)d_in[9];
  const float* W3 = (const float*)d_in[10], *b3 = (const float*)d_in[11];
  const float* g3 = (const float*)d_in[12], *be3 = (const float*)d_in[13];
  float* out0 = (float*)d_out;                 // xyz_query_pc [16,3,1024]
  float* out1 = out0 + B_ * 3 * S_;            // new_points   [16,128,1024]

  char* ws = (char*)d_ws;
  float* new_xyz  = (float*)(ws);
  float* bn1      = (float*)(ws + 196608);
  float* bn2      = bn1 + 128;
  int*   prog     = (int*)(ws + 198656);                           // 16 ints (old gidx spot)
  float* partials = (float*)(ws + 2295808);
  unsigned short* y1 = (unsigned short*)(ws + 4392960);            // 64 MB bf16
  unsigned short* y2 = (unsigned short*)(ws + 4392960 + 67108864); // 64 MB bf16 (K-permuted)
  float* mnbuf = (float*)(ws + 4392960);                           // reuse y1 space
  float* mxbuf = (float*)(ws + 4392960 + 8388608);

  hipMemsetAsync(prog, 0, 64, stream);   // reset progress flags each replay
  head_kernel<<<B_ + NWORK, 512, 0, stream>>>(xyz, pts, W1, b1, out0, new_xyz, prog, y1, partials);
  finalize_kernel<<<64, 256, 0, stream>>>(partials, 64, NWORK, g1, be1, bn1);
  layer2_kernel<<<PNB, 256, 0, stream>>>(y1, W2, b2, bn1, y2, partials);
  finalize_kernel<<<64, 256, 0, stream>>>(partials, 64, PNB, g2, be2, bn2);
  l3fused_kernel<<<PNB, 256, 0, stream>>>(y2, W3, b3, bn2, mnbuf, mxbuf, partials);
  l3final_kernel<<<8192, 256, 0, stream>>>(partials, g3, be3, mnbuf, mxbuf, out1);
}